// Round 6
// baseline (419.115 us; speedup 1.0000x reference)
//
#include <hip/hip_runtime.h>
#include <stdint.h>

// GiddLinearNoise.sample_zt on MI355X (gfx950).
//
// z_t[b,s] = argmax_v ( ((1-t_b)*onehot(id)[v] + t_b*pi[v]) / (1e-10 - log(u[b,s,v] + 1e-10)) )
// u = jax.random.uniform(key(1), (4,1024,50257), f32), partitionable threefry stream:
// bits[i] = fold(threefry2x32(key=(0,1), counter=(0,i))) = y0 ^ y1;  u = (bits>>9) * 2^-23.
//
// All generic tokens share ONE probability float => q is strictly monotone in the 23-bit
// mantissa k, so the generic argmax is (max k, min v on tie), log-free. id/MASK positions
// are included in the scan; their exact candidates (strictly larger p, same u) dominate any
// spurious win, so the 3-candidate exact epilogue is correct (round-2 derivation).
//
// Round 4/5: the WHOLE pair body is ONE asm block — two interleaved threefry chains
// (independent dep-chains, zero compiler seams) + v_and_or select + v_max3 accumulate:
// 136 pinned VALU per 2 elements (+1 counter add outside) = 68.5 VALU/elem, within 4%
// of the 66-op cipher floor. Packed key = (k<<9)|pos, pos=((127-pair)<<1)|isA.

namespace {

constexpr int VOCAB = 50257;
constexpr int MASK  = 50256;   // last index
constexpr int TPB   = 256;
constexpr int NROWS = 4096;    // B*S

// One threefry round for both chains, interleaved. a0=%1 a1=%2 b0=%3 b1=%4.
// x0 += x1; x1 = rotl(x1, r) ^ x0   with rr = 32 - r  (alignbit is rotr).
#define RAB(rr) \
  "v_add_u32 %1, %1, %2\n\t" \
  "v_add_u32 %3, %3, %4\n\t" \
  "v_alignbit_b32 %2, %2, %2, " #rr "\n\t" \
  "v_alignbit_b32 %4, %4, %4, " #rr "\n\t" \
  "v_xor_b32 %2, %2, %1\n\t" \
  "v_xor_b32 %4, %4, %3\n\t"

// Round whose x0-add folds the +1 key-schedule injection (after s=1 and s=4).
#define RAB_P1(rr) \
  "v_add3_u32 %1, %1, %2, 1\n\t" \
  "v_add3_u32 %3, %3, %4, 1\n\t" \
  "v_alignbit_b32 %2, %2, %2, " #rr "\n\t" \
  "v_alignbit_b32 %4, %4, %4, " #rr "\n\t" \
  "v_xor_b32 %2, %2, %1\n\t" \
  "v_xor_b32 %4, %4, %3\n\t"

// Round whose x0-add folds the +ks2 injection (after s=2). %7 = ks2 (SGPR).
#define RAB_PK(rr) \
  "v_add3_u32 %1, %1, %2, %7\n\t" \
  "v_add3_u32 %3, %3, %4, %7\n\t" \
  "v_alignbit_b32 %2, %2, %2, " #rr "\n\t" \
  "v_alignbit_b32 %4, %4, %4, " #rr "\n\t" \
  "v_xor_b32 %2, %2, %1\n\t" \
  "v_xor_b32 %4, %4, %3\n\t"

// x1-side injection for both chains (literal/inline constant).
#define INJ1(c) \
  "v_add_u32 %2, " c ", %2\n\t" \
  "v_add_u32 %4, " c ", %4\n\t"

// Threefry-2x32-20, key (0,1), counters (0, hA-1) and (0, hA+255) [ks1=1 pre-folded],
// fold y0^y1, pack (k<<9)|pos, accumulate max into km. 136 VALU instructions.
// %0=km(+v) %1=a0 %2=a1 %3=b0 %4=b1 (=&v) %5=hA(v) %6=vmask(v) %7=ks2(s) %8=posA(s) %9=posB(s)
#define PAIR_BODY \
  "v_add_u32 %3, 0x100, %5\n\t"            /* hB = hA + 256 */ \
  /* r1: x0 = h, x1 = rotl(h,13)^h */ \
  "v_alignbit_b32 %2, %5, %5, 19\n\t" \
  "v_alignbit_b32 %4, %3, %3, 19\n\t" \
  "v_xor_b32 %2, %2, %5\n\t" \
  "v_xor_b32 %4, %4, %3\n\t" \
  /* r2 (A reads x0 from hA=%5) */ \
  "v_add_u32 %1, %5, %2\n\t" \
  "v_add_u32 %3, %3, %4\n\t" \
  "v_alignbit_b32 %2, %2, %2, 17\n\t" \
  "v_alignbit_b32 %4, %4, %4, 17\n\t" \
  "v_xor_b32 %2, %2, %1\n\t" \
  "v_xor_b32 %4, %4, %3\n\t" \
  RAB(6)  RAB(26) \
  INJ1("0x1BD11BDC")                       /* s=1: x1 += ks2+1 (x0+=1 folded in r5) */ \
  RAB_P1(15) RAB(3) RAB(16) RAB(8) \
  INJ1("2")                                /* s=2: x1 += 2 (x0+=ks2 folded in r9) */ \
  RAB_PK(19) RAB(17) RAB(6) RAB(26) \
  INJ1("4")                                /* s=3: x1 += 4 (x0 += 0) */ \
  RAB(15) RAB(3) RAB(16) RAB(8) \
  INJ1("0x1BD11BDF")                       /* s=4: x1 += ks2+4 (x0+=1 folded in r17) */ \
  RAB_P1(19) RAB(17) RAB(6) RAB(26) \
  /* final injection (ks2, 5) + fold */ \
  "v_add_u32 %1, %7, %1\n\t" \
  "v_add_u32 %3, %7, %3\n\t" \
  "v_add_u32 %2, 5, %2\n\t" \
  "v_add_u32 %4, 5, %4\n\t" \
  "v_xor_b32 %1, %1, %2\n\t" \
  "v_xor_b32 %3, %3, %4\n\t" \
  /* pack: key = (bits & 0xFFFFFE00) | pos */ \
  "v_and_or_b32 %1, %1, %6, %8\n\t" \
  "v_and_or_b32 %3, %3, %6, %9\n\t" \
  "v_max3_u32 %0, %1, %3, %0"

// Single-chain threefry fold (epilogue / peel) — verified in round 3.
__device__ __forceinline__ uint32_t tf_fold(uint32_t h, uint32_t ks2) {
  uint32_t x0, x1;
  asm("v_alignbit_b32 %1, %2, %2, 19\n\t"
      "v_xor_b32 %1, %1, %2\n\t"
      "v_add_u32 %0, %2, %1\n\t"
      "v_alignbit_b32 %1, %1, %1, 17\n\t"
      "v_xor_b32 %1, %1, %0\n\t"
      "v_add_u32 %0, %0, %1\n\t"
      "v_alignbit_b32 %1, %1, %1, 6\n\t"
      "v_xor_b32 %1, %1, %0\n\t"
      "v_add_u32 %0, %0, %1\n\t"
      "v_alignbit_b32 %1, %1, %1, 26\n\t"
      "v_xor_b32 %1, %1, %0\n\t"
      "v_add_u32 %1, 0x1BD11BDC, %1\n\t"
      "v_add3_u32 %0, %0, %1, 1\n\t"
      "v_alignbit_b32 %1, %1, %1, 15\n\t"
      "v_xor_b32 %1, %1, %0\n\t"
      "v_add_u32 %0, %0, %1\n\t"
      "v_alignbit_b32 %1, %1, %1, 3\n\t"
      "v_xor_b32 %1, %1, %0\n\t"
      "v_add_u32 %0, %0, %1\n\t"
      "v_alignbit_b32 %1, %1, %1, 16\n\t"
      "v_xor_b32 %1, %1, %0\n\t"
      "v_add_u32 %0, %0, %1\n\t"
      "v_alignbit_b32 %1, %1, %1, 8\n\t"
      "v_xor_b32 %1, %1, %0\n\t"
      "v_add_u32 %1, 2, %1\n\t"
      "v_add3_u32 %0, %0, %1, %3\n\t"
      "v_alignbit_b32 %1, %1, %1, 19\n\t"
      "v_xor_b32 %1, %1, %0\n\t"
      "v_add_u32 %0, %0, %1\n\t"
      "v_alignbit_b32 %1, %1, %1, 17\n\t"
      "v_xor_b32 %1, %1, %0\n\t"
      "v_add_u32 %0, %0, %1\n\t"
      "v_alignbit_b32 %1, %1, %1, 6\n\t"
      "v_xor_b32 %1, %1, %0\n\t"
      "v_add_u32 %0, %0, %1\n\t"
      "v_alignbit_b32 %1, %1, %1, 26\n\t"
      "v_xor_b32 %1, %1, %0\n\t"
      "v_add_u32 %1, 4, %1\n\t"
      "v_add_u32 %0, %0, %1\n\t"
      "v_alignbit_b32 %1, %1, %1, 15\n\t"
      "v_xor_b32 %1, %1, %0\n\t"
      "v_add_u32 %0, %0, %1\n\t"
      "v_alignbit_b32 %1, %1, %1, 3\n\t"
      "v_xor_b32 %1, %1, %0\n\t"
      "v_add_u32 %0, %0, %1\n\t"
      "v_alignbit_b32 %1, %1, %1, 16\n\t"
      "v_xor_b32 %1, %1, %0\n\t"
      "v_add_u32 %0, %0, %1\n\t"
      "v_alignbit_b32 %1, %1, %1, 8\n\t"
      "v_xor_b32 %1, %1, %0\n\t"
      "v_add_u32 %1, 0x1BD11BDF, %1\n\t"
      "v_add3_u32 %0, %0, %1, 1\n\t"
      "v_alignbit_b32 %1, %1, %1, 19\n\t"
      "v_xor_b32 %1, %1, %0\n\t"
      "v_add_u32 %0, %0, %1\n\t"
      "v_alignbit_b32 %1, %1, %1, 17\n\t"
      "v_xor_b32 %1, %1, %0\n\t"
      "v_add_u32 %0, %0, %1\n\t"
      "v_alignbit_b32 %1, %1, %1, 6\n\t"
      "v_xor_b32 %1, %1, %0\n\t"
      "v_add_u32 %0, %0, %1\n\t"
      "v_alignbit_b32 %1, %1, %1, 26\n\t"
      "v_xor_b32 %1, %1, %0\n\t"
      "v_add_u32 %0, %3, %0\n\t"
      "v_add_u32 %1, 5, %1\n\t"
      "v_xor_b32 %0, %0, %1"
      : "=&v"(x0), "=&v"(x1)
      : "v"(h), "s"(ks2));
  return x0;
}

// Exact replica of the reference float32 pipeline for one candidate.
__device__ __forceinline__ float qval(float p, uint32_t k) {
  const float u = (float)k * 0x1p-23f;          // == jax uniform value, exact
  const float g = 1e-10f - logf(u + 1e-10f);    // gumbel_norm (g > 0 always)
  return p / g;                                  // IEEE f32 divide
}

__global__ __launch_bounds__(TPB) void gidd_sample_zt(
    const int* __restrict__ ids, const float* __restrict__ t,
    const float* __restrict__ pi, int* __restrict__ out) {
  const int row = blockIdx.x;       // b*1024 + s
  const int b = row >> 10;
  const int tid = threadIdx.x;

  const int id = ids[row];
  const uint32_t base = (uint32_t)row * (uint32_t)VOCAB;
  const uint32_t ks2 = 0x1BD11BDBu;

  // k-field mask in a VGPR so v_and_or_b32's single SGPR slot goes to the uniform pos.
  uint32_t vmask;
  asm("v_mov_b32 %0, 0xFFFFFE00" : "=v"(vmask));

  // Generic scan over v = it*256 + tid, it in [0,197). Packed key = (k<<9) | pos,
  // pos = ((127-ii)<<1) | isA for the pair (itA=2*ii, itB=2*ii+1).
  uint32_t km = 0u;
  uint32_t hA = base + (uint32_t)tid + 1u;   // counter + ks1(=1) for element A

#pragma unroll 1
  for (uint32_t ii = 0; ii < 98u; ++ii) {
    const uint32_t posA = (((127u - ii) << 1) | 1u);  // uniform -> SGPR (s_alu updates)
    const uint32_t posB = ((127u - ii) << 1);
    uint32_t a0, a1, b0, b1;
    asm(PAIR_BODY
        : "+v"(km), "=&v"(a0), "=&v"(a1), "=&v"(b0), "=&v"(b1)
        : "v"(hA), "v"(vmask), "s"(ks2), "s"(posA), "s"(posB));
    hA += 512u;
  }
  // Peel it = 196 (pos = ((127-98)<<1)|1 = 59): v = 50176 + tid, valid to v = 50256
  // (MASK included in scan: safe per the domination argument).
  if (tid <= 80) {
    const uint32_t bits = tf_fold(hA, ks2);
    uint32_t key;
    asm("v_and_or_b32 %0, %1, %2, %3" : "=v"(key) : "v"(bits), "v"(vmask), "s"(59u));
    km = km > key ? km : key;
  }

  // Wave max; min-lane tie pick => exact (max k, min v).
  uint32_t kw = km;
#pragma unroll
  for (int off = 32; off > 0; off >>= 1) {
    const uint32_t o = __shfl_xor(kw, off);
    kw = kw > o ? kw : o;
  }
  const uint64_t bal = __ballot(km == kw);
  const int lane0 = __ffsll((unsigned long long)bal) - 1;
  const int wid = tid >> 6;
  const uint32_t pos = kw & 0x1FFu;
  const int it = 255 - 2 * (int)((pos >> 1) & 0x7Fu) - (int)(pos & 1u);
  const int vw = it * 256 + (wid << 6) + lane0;

  __shared__ uint32_t skm[4];
  __shared__ int svm[4];
  if ((tid & 63) == 0) { skm[wid] = kw; svm[wid] = vw; }
  __syncthreads();

  if (tid == 0) {
    uint32_t kb = skm[0]; int vb = svm[0];
    for (int w = 1; w < 4; ++w)
      if (skm[w] > kb || (skm[w] == kb && svm[w] < vb)) { kb = skm[w]; vb = svm[w]; }
    const uint32_t kwin = kb >> 9;            // 23-bit mantissa of the generic winner

    const float tb = t[b];
    const float pic = pi[0];        // generic pi value (identical bits for all non-mask v)
    const float pim = pi[MASK];
    const float a = 1.0f - tb;      // alpha_t
    const float pc = tb * pic;      // generic prob
    const float pm = tb * pim;      // mask prob (without onehot)

    const uint32_t kmsk = tf_fold(base + (uint32_t)MASK + 1u, ks2) >> 9;
    const uint32_t kid  = tf_fold(base + (uint32_t)id + 1u, ks2) >> 9;

    float bq = qval(pc, kwin);
    int bv = vb;
    // MASK candidate: p strictly > pc => never ties the generic winner; index is max.
    const float pmask = (id == MASK) ? (pm + a) : pm;
    const float qm = qval(pmask, kmsk);
    if (qm > bq) { bq = qm; bv = MASK; }
    // input-id candidate (first-index-of-max rule).
    if (id != MASK) {
      const float qi = qval(pc + a, kid);
      if (qi > bq || (qi == bq && id < bv)) { bq = qi; bv = id; }
    }
    out[row] = bv;
  }
}

}  // namespace

extern "C" void kernel_launch(void* const* d_in, const int* in_sizes, int n_in,
                              void* d_out, int out_size, void* d_ws, size_t ws_size,
                              hipStream_t stream) {
  const int* ids  = (const int*)d_in[0];
  const float* t  = (const float*)d_in[1];
  const float* pi = (const float*)d_in[2];
  int* out = (int*)d_out;
  gidd_sample_zt<<<NROWS, TPB, 0, stream>>>(ids, t, pi, out);
}